// Round 7
// baseline (257.954 us; speedup 1.0000x reference)
//
#include <hip/hip_runtime.h>
#include <hip/hip_bf16.h>

// SAGAN self-attention v7. B=8, C=64, N=4096, CQ=8.
// prep (verbatim R5, verified): Qp/Kp [B][N][16] bf16 (ch8-15 zero, Q scaled
//   log2e), V = Wv.x+bv [B][C][N] bf16.
// attn: grid 1024 = (b, 32q-tile), 256 thr = 4 waves, wave = all 32 q x
//   j-quarter (32 steps x 32 j). Software-pipelined (R6 body, 2-deep):
//   step s: [read P(s-1) b128; p2(s-1) MFMA w/ V(s-1) regs; prefetch
//   K/V(s+1); p1(s) K=16 MFMA; exp2; write P(s)]. P wave-private, row
//   stride 96 B -> b64 writes 4 dw/bank, b128 reads 8 dw/bank (uniform).
//   No barriers in main loop. 4 waves/SIMD occupancy (2x R4-R6).

#define B_   8
#define C_   64
#define N_   4096
#define LOG2E 1.44269504088896340736f

typedef short bf16x8 __attribute__((ext_vector_type(8)));
typedef short bf16x4 __attribute__((ext_vector_type(4)));
typedef float f32x4  __attribute__((ext_vector_type(4)));
typedef unsigned int uint32;

#if __has_builtin(__builtin_amdgcn_exp2f)
#define EXP2(x) __builtin_amdgcn_exp2f(x)
#else
#define EXP2(x) __expf((x) * 0.69314718055994530942f)
#endif

__device__ __forceinline__ unsigned short f2bf_rn(float f) {
    union { __hip_bfloat16 h; unsigned short u; } cv;
    cv.h = __float2bfloat16(f);
    return cv.u;
}
__device__ __forceinline__ uint32 pk_rn(float lo, float hi) {
    return (uint32)f2bf_rn(lo) | ((uint32)f2bf_rn(hi) << 16);
}
// RTZ pack (1 v_perm): truncation bias cancels in softmax ratio (R2-R5 proven)
__device__ __forceinline__ uint32 pack_rtz(float lo, float hi) {
    return __builtin_amdgcn_perm(__float_as_uint(hi), __float_as_uint(lo), 0x07060302);
}

// ---------------------------------------------------------------------------
// prep (R5 verbatim, verified): all-MFMA QKV.
// ---------------------------------------------------------------------------
__global__ __launch_bounds__(256) void prep_kernel(
    const float* __restrict__ x,
    const float* __restrict__ wq, const float* __restrict__ bq,
    const float* __restrict__ wk, const float* __restrict__ bk,
    const float* __restrict__ wv, const float* __restrict__ bv,
    unsigned short* __restrict__ Qp, unsigned short* __restrict__ Kp,
    unsigned short* __restrict__ V)
{
    __shared__ __align__(16) unsigned short Wb[80 * 72];
    __shared__ __align__(16) unsigned short xT[64 * 72];

    const int t  = threadIdx.x;
    const int b  = blockIdx.x >> 6;
    const int p0 = (blockIdx.x & 63) << 6;

    for (int i = t; i < 5120; i += 256) {
        int o = i >> 6;
        float v = (o < 8) ? wq[i] * LOG2E : (o < 16) ? wk[i - 512] : wv[i - 1024];
        Wb[o * 72 + (i & 63)] = f2bf_rn(v);
    }
    for (int i = t; i < 2048; i += 256) {
        int c = i >> 5, p2 = (i & 31) << 1;
        float2 v = *(const float2*)(x + ((size_t)b * C_ + c) * N_ + p0 + p2);
        xT[p2 * 72 + c]       = f2bf_rn(v.x);
        xT[(p2 + 1) * 72 + c] = f2bf_rn(v.y);
    }
    __syncthreads();

    const int w = t >> 6, lane = t & 63, l16 = lane & 15, qd = lane >> 4;

    bf16x8 bfr[2];
    #pragma unroll
    for (int ks = 0; ks < 2; ++ks)
        bfr[ks] = *(const bf16x8*)(xT + (w * 16 + l16) * 72 + ks * 32 + qd * 8);
    const int px = p0 + w * 16 + l16;

    {   // Q/K rows 0..15
        f32x4 acc;
        #pragma unroll
        for (int r = 0; r < 4; ++r) {
            int o = qd * 4 + r;
            acc[r] = (o < 8) ? bq[o] * LOG2E : bk[o - 8];
        }
        bf16x8 af0 = *(const bf16x8*)(Wb + l16 * 72 + qd * 8);
        bf16x8 af1 = *(const bf16x8*)(Wb + l16 * 72 + 32 + qd * 8);
        acc = __builtin_amdgcn_mfma_f32_16x16x32_bf16(af0, bfr[0], acc, 0, 0, 0);
        acc = __builtin_amdgcn_mfma_f32_16x16x32_bf16(af1, bfr[1], acc, 0, 0, 0);
        uint2 u;
        u.x = pk_rn(acc[0], acc[1]);
        u.y = pk_rn(acc[2], acc[3]);
        unsigned short* base = (qd < 2) ? Qp : Kp;
        size_t row = ((size_t)b * N_ + px) * 16;
        *(uint2*)(base + row + (qd & 1) * 4) = u;
        uint2 z; z.x = 0; z.y = 0;
        *(uint2*)(base + row + 8 + (qd & 1) * 4) = z;   // zero ch 8-15
    }
    #pragma unroll
    for (int mt = 1; mt < 5; ++mt) {   // V rows
        const int ch = mt * 16 + qd * 4 - 16;
        f32x4 acc = {bv[ch], bv[ch + 1], bv[ch + 2], bv[ch + 3]};
        bf16x8 af0 = *(const bf16x8*)(Wb + (mt * 16 + l16) * 72 + qd * 8);
        bf16x8 af1 = *(const bf16x8*)(Wb + (mt * 16 + l16) * 72 + 32 + qd * 8);
        acc = __builtin_amdgcn_mfma_f32_16x16x32_bf16(af0, bfr[0], acc, 0, 0, 0);
        acc = __builtin_amdgcn_mfma_f32_16x16x32_bf16(af1, bfr[1], acc, 0, 0, 0);
        #pragma unroll
        for (int r = 0; r < 4; ++r)
            V[((size_t)b * C_ + ch + r) * N_ + px] = f2bf_rn(acc[r]);
    }
}

// ---------------------------------------------------------------------------
// attn. Grid 1024 = (b, 32q), 256 thr = 4 waves, wave = j-quarter.
// ---------------------------------------------------------------------------
__global__ __launch_bounds__(256, 4) void attn_mfma5_kernel(
    const unsigned short* __restrict__ Qp,
    const unsigned short* __restrict__ Kp,
    const unsigned short* __restrict__ Vb,
    float* __restrict__ out)
{
    // P: wave*6144 + buf*3072 + qt*1536 + l16*96 (+ jt*32 + qd*8 wr / qd*16 rd)
    // Dn at 24576 (4 waves x 32 q fp32); epilogue reduce reuses [0, 8192)
    __shared__ __align__(16) char smem[25088];

    const int t    = threadIdx.x;
    const int w    = t >> 6;
    const int lane = t & 63;
    const int l16  = lane & 15;
    const int qd   = lane >> 4;
    const int b    = blockIdx.x >> 7;          // 128 q-tiles per batch
    const int i0   = (blockIdx.x & 127) << 5;  // 32 queries

    const f32x4 zf = {};

    // Q frags (B-operand of K=16 MFMA), rows zero-padded ch 8-15
    bf16x4 qf[2];
    #pragma unroll
    for (int qt = 0; qt < 2; ++qt)
        qf[qt] = *(const bf16x4*)(Qp + ((size_t)b * N_ + i0 + qt * 16 + l16) * 16 + qd * 4);

    const unsigned short* Kq = Kp + ((size_t)b * N_ + w * 1024) * 16;
    const unsigned short* Vq = Vb + (size_t)b * C_ * N_ + w * 1024;

    char* PW = smem + w * 6144;
    const int wr = l16 * 96 + (qd << 3);   // + jt*32 bytes; b64 writes 4 dw/bank
    const int rd = l16 * 96 + (qd << 4);   // b128 reads 8 dw/bank

    f32x4 acc[2][4];   // [qt][ct]: O^T rows c=ct*16+qd*4+r, col q=qt*16+l16
    #pragma unroll
    for (int qt = 0; qt < 2; ++qt)
        #pragma unroll
        for (int ct = 0; ct < 4; ++ct) acc[qt][ct] = zf;
    float dsum[2] = {0.f, 0.f};

    bf16x4 kf[2][2];
    bf16x8 vf[2][4];

    // ---- prologue: step 0 P, prefetch step 1 ----
    #pragma unroll
    for (int jt = 0; jt < 2; ++jt)
        kf[0][jt] = *(const bf16x4*)(Kq + (size_t)(jt * 16 + l16) * 16 + qd * 4);
    #pragma unroll
    for (int ct = 0; ct < 4; ++ct)
        vf[0][ct] = *(const bf16x8*)(Vq + (size_t)(ct * 16 + l16) * N_ + qd * 8);

    #pragma unroll
    for (int jt = 0; jt < 2; ++jt) {
        f32x4 sf[2];
        #pragma unroll
        for (int qt = 0; qt < 2; ++qt)
            sf[qt] = __builtin_amdgcn_mfma_f32_16x16x16bf16_1k(kf[0][jt], qf[qt], zf, 0, 0, 0);
        #pragma unroll
        for (int qt = 0; qt < 2; ++qt) {
            float e0 = EXP2(sf[qt][0]), e1 = EXP2(sf[qt][1]);
            float e2 = EXP2(sf[qt][2]), e3 = EXP2(sf[qt][3]);
            dsum[qt] += (e0 + e1) + (e2 + e3);
            uint2 u; u.x = pack_rtz(e0, e1); u.y = pack_rtz(e2, e3);
            *(uint2*)(PW + qt * 1536 + wr + jt * 32) = u;
        }
    }
    #pragma unroll
    for (int jt = 0; jt < 2; ++jt)
        kf[1][jt] = *(const bf16x4*)(Kq + (size_t)(32 + jt * 16 + l16) * 16 + qd * 4);
    #pragma unroll
    for (int ct = 0; ct < 4; ++ct)
        vf[1][ct] = *(const bf16x8*)(Vq + (size_t)(ct * 16 + l16) * N_ + 32 + qd * 8);

    // ---- main pipelined loop ----
    #pragma unroll 2
    for (int s = 1; s < 32; ++s) {
        const int cur = s & 1, prv = cur ^ 1;
        const int jb = s * 32;

        // p2(s-1): read P(s-1), MFMA with V(s-1)
        bf16x8 pb[2];
        #pragma unroll
        for (int qt = 0; qt < 2; ++qt)
            pb[qt] = *(const bf16x8*)(PW + prv * 3072 + qt * 1536 + rd);
        #pragma unroll
        for (int qt = 0; qt < 2; ++qt)
            #pragma unroll
            for (int ct = 0; ct < 4; ++ct)
                acc[qt][ct] = __builtin_amdgcn_mfma_f32_16x16x32_bf16(vf[prv][ct], pb[qt], acc[qt][ct], 0, 0, 0);

        // prefetch step s+1 into freed slots
        if (s < 31) {
            #pragma unroll
            for (int jt = 0; jt < 2; ++jt)
                kf[prv][jt] = *(const bf16x4*)(Kq + (size_t)(jb + 32 + jt * 16 + l16) * 16 + qd * 4);
            #pragma unroll
            for (int ct = 0; ct < 4; ++ct)
                vf[prv][ct] = *(const bf16x8*)(Vq + (size_t)(ct * 16 + l16) * N_ + jb + 32 + qd * 8);
        }

        // p1(s) + exp + write P(s)
        #pragma unroll
        for (int jt = 0; jt < 2; ++jt) {
            f32x4 sf[2];
            #pragma unroll
            for (int qt = 0; qt < 2; ++qt)
                sf[qt] = __builtin_amdgcn_mfma_f32_16x16x16bf16_1k(kf[cur][jt], qf[qt], zf, 0, 0, 0);
            #pragma unroll
            for (int qt = 0; qt < 2; ++qt) {
                float e0 = EXP2(sf[qt][0]), e1 = EXP2(sf[qt][1]);
                float e2 = EXP2(sf[qt][2]), e3 = EXP2(sf[qt][3]);
                dsum[qt] += (e0 + e1) + (e2 + e3);
                uint2 u; u.x = pack_rtz(e0, e1); u.y = pack_rtz(e2, e3);
                *(uint2*)(PW + cur * 3072 + qt * 1536 + wr + jt * 32) = u;
            }
        }
    }

    // ---- pipeline epilogue: p2(31) ----
    {
        bf16x8 pb[2];
        #pragma unroll
        for (int qt = 0; qt < 2; ++qt)
            pb[qt] = *(const bf16x8*)(PW + 3072 + qt * 1536 + rd);
        #pragma unroll
        for (int qt = 0; qt < 2; ++qt)
            #pragma unroll
            for (int ct = 0; ct < 4; ++ct)
                acc[qt][ct] = __builtin_amdgcn_mfma_f32_16x16x32_bf16(vf[1][ct], pb[qt], acc[qt][ct], 0, 0, 0);
    }

    // ---- denominator partials -> Dn[w][q] ----
    float* Dn = (float*)(smem + 24576);
    #pragma unroll
    for (int qt = 0; qt < 2; ++qt) {
        float v = dsum[qt];
        v += __shfl_xor(v, 16, 64);
        v += __shfl_xor(v, 32, 64);
        if (qd == 0) Dn[w * 32 + qt * 16 + l16] = v;
    }
    __syncthreads();

    // ---- 3-round cross-wave acc reduction into wave 0 ----
    float* rb = (float*)smem;
    #pragma unroll
    for (int rnd = 1; rnd < 4; ++rnd) {
        if (w == rnd) {
            #pragma unroll
            for (int qt = 0; qt < 2; ++qt)
                #pragma unroll
                for (int ct = 0; ct < 4; ++ct)
                    *(f32x4*)(rb + ((qt * 4 + ct) * 64 + lane) * 4) = acc[qt][ct];
        }
        __syncthreads();
        if (w == 0) {
            #pragma unroll
            for (int qt = 0; qt < 2; ++qt)
                #pragma unroll
                for (int ct = 0; ct < 4; ++ct) {
                    f32x4 p = *(const f32x4*)(rb + ((qt * 4 + ct) * 64 + lane) * 4);
                    acc[qt][ct] += p;
                }
        }
        __syncthreads();
    }

    if (w == 0) {
        #pragma unroll
        for (int qt = 0; qt < 2; ++qt) {
            const int q = qt * 16 + l16;
            const float inv = 1.0f / (Dn[q] + Dn[32 + q] + Dn[64 + q] + Dn[96 + q]);
            #pragma unroll
            for (int ct = 0; ct < 4; ++ct)
                #pragma unroll
                for (int r = 0; r < 4; ++r)
                    out[((size_t)b * C_ + ct * 16 + qd * 4 + r) * N_ + i0 + q] = acc[qt][ct][r] * inv;
        }
    }
}

// ---------------------------------------------------------------------------
// Fallback (workspace too small): round-1 fused fp32 flash kernel (verified).
// ---------------------------------------------------------------------------
__global__ __launch_bounds__(256) void attn_fused_fallback(
    const float* __restrict__ x,
    const float* __restrict__ wq, const float* __restrict__ bq,
    const float* __restrict__ wk, const float* __restrict__ bk,
    const float* __restrict__ wv, const float* __restrict__ bv,
    float* __restrict__ out)
{
    __shared__ float Qs[64][8];
    __shared__ float Ks[8][64];
    __shared__ float Vs[64][C_];
    __shared__ float Ws[64][64 + 1];
    __shared__ float Xs[C_ * 64];
    __shared__ float Wks[8][C_];
    __shared__ float Wvs[C_][C_ + 1];

    const int t     = threadIdx.x;
    const int b     = blockIdx.x / (N_ / 64);
    const int i0    = (blockIdx.x % (N_ / 64)) * 64;
    const int jlane = t & 63;
    const int wgrp  = t >> 6;

    for (int l = t; l < 8 * C_;  l += 256) Wks[l >> 6][l & 63] = wk[l];
    for (int l = t; l < C_ * C_; l += 256) Wvs[l >> 6][l & 63] = wv[l];
    for (int l = t; l < C_ * 64; l += 256)
        Xs[(l >> 6) * 64 + (l & 63)] = x[((size_t)b * C_ + (l >> 6)) * N_ + i0 + (l & 63)];
    __syncthreads();
    {
        int qi = jlane;
        #pragma unroll
        for (int r = 0; r < 2; ++r) {
            int cc = wgrp * 2 + r;
            float a = bq[cc];
            for (int c = 0; c < C_; ++c) a += wq[cc * C_ + c] * Xs[c * 64 + qi];
            Qs[qi][cc] = a;
        }
    }
    __syncthreads();

    const int qi2 = t >> 2;
    const int cb  = (t & 3) << 4;
    float accv[16];
    #pragma unroll
    for (int r = 0; r < 16; ++r) accv[r] = 0.f;
    float denom = 0.f;

    for (int j0 = 0; j0 < N_; j0 += 64) {
        for (int l = t; l < C_ * 64; l += 256)
            Xs[(l >> 6) * 64 + (l & 63)] = x[((size_t)b * C_ + (l >> 6)) * N_ + j0 + (l & 63)];
        __syncthreads();
        {
            int j = jlane;
            #pragma unroll
            for (int r = 0; r < 2; ++r) {
                int cc = wgrp * 2 + r;
                float a = bk[cc];
                for (int c = 0; c < C_; ++c) a += Wks[cc][c] * Xs[c * 64 + j];
                Ks[cc][j] = a;
            }
        }
        {
            int vc = jlane;
            #pragma unroll 2
            for (int r = 0; r < 16; ++r) {
                int j = wgrp * 16 + r;
                float a = bv[vc];
                for (int c = 0; c < C_; ++c) a += Wvs[vc][c] * Xs[c * 64 + j];
                Vs[j][vc] = a;
            }
        }
        __syncthreads();
        {
            float kreg[8];
            #pragma unroll
            for (int cc = 0; cc < 8; ++cc) kreg[cc] = Ks[cc][jlane];
            #pragma unroll 4
            for (int r = 0; r < 16; ++r) {
                int qi = wgrp * 16 + r;
                float e = 0.f;
                #pragma unroll
                for (int cc = 0; cc < 8; ++cc) e += Qs[qi][cc] * kreg[cc];
                Ws[qi][jlane] = __expf(e);
            }
        }
        __syncthreads();
        #pragma unroll 4
        for (int j = 0; j < 64; ++j) {
            float wv2 = Ws[qi2][j];
            denom += wv2;
            const float4* vrow = (const float4*)(&Vs[j][cb]);
            float4 v0 = vrow[0], v1 = vrow[1], v2 = vrow[2], v3 = vrow[3];
            accv[0]  += wv2 * v0.x; accv[1]  += wv2 * v0.y; accv[2]  += wv2 * v0.z; accv[3]  += wv2 * v0.w;
            accv[4]  += wv2 * v1.x; accv[5]  += wv2 * v1.y; accv[6]  += wv2 * v1.z; accv[7]  += wv2 * v1.w;
            accv[8]  += wv2 * v2.x; accv[9]  += wv2 * v2.y; accv[10] += wv2 * v2.z; accv[11] += wv2 * v2.w;
            accv[12] += wv2 * v3.x; accv[13] += wv2 * v3.y; accv[14] += wv2 * v3.z; accv[15] += wv2 * v3.w;
        }
        __syncthreads();
    }

    const float inv = 1.0f / denom;
    #pragma unroll
    for (int r = 0; r < 16; ++r)
        out[((size_t)b * C_ + cb + r) * N_ + i0 + qi2] = accv[r] * inv;
}

// ---------------------------------------------------------------------------
extern "C" void kernel_launch(void* const* d_in, const int* in_sizes, int n_in,
                              void* d_out, int out_size, void* d_ws, size_t ws_size,
                              hipStream_t stream)
{
    const float* x  = (const float*)d_in[0];
    const float* wq = (const float*)d_in[1];
    const float* bq = (const float*)d_in[2];
    const float* wk = (const float*)d_in[3];
    const float* bk = (const float*)d_in[4];
    const float* wv = (const float*)d_in[5];
    const float* bv = (const float*)d_in[6];
    float* out = (float*)d_out;

    const size_t nQ = (size_t)B_ * N_ * 16;       // 512K elems (1 MB)
    const size_t nV = (size_t)B_ * C_ * N_;       // 2M elems (4 MB)
    const size_t needed = (2 * nQ + nV) * sizeof(unsigned short);   // 6 MB

    if (ws_size >= needed) {
        unsigned short* Qp = (unsigned short*)d_ws;
        unsigned short* Kp = Qp + nQ;
        unsigned short* Vb = Kp + nQ;
        prep_kernel<<<B_ * (N_ / 64), 256, 0, stream>>>(x, wq, bq, wk, bk, wv, bv,
                                                        Qp, Kp, Vb);
        attn_mfma5_kernel<<<B_ * (N_ / 32), 256, 0, stream>>>(Qp, Kp, Vb, out);
    } else {
        attn_fused_fallback<<<B_ * (N_ / 64), 256, 0, stream>>>(x, wq, bq, wk, bk, wv, bv, out);
    }
}

// Round 8
// 156.950 us; speedup vs baseline: 1.6435x; 1.6435x over previous
//
#include <hip/hip_runtime.h>
#include <hip/hip_bf16.h>

// SAGAN self-attention v8. B=8, C=64, N=4096, CQ=8.
// == R7 with ONE change: attn __launch_bounds__(256) with NO min-waves arg.
// R7's __launch_bounds__(256,4) capped VGPRs at 128 -> allocator spilled the
// pipeline state to scratch (WRITE_SIZE 235 MB, 900 B/thread) -> 190 us.
// Natural allocation (~84-130 VGPR, R5 evidence) has zero scratch.
//
// prep (R5 verbatim, verified): Qp/Kp [B][N][16] bf16 (ch8-15 zero, Q scaled
//   log2e), V = Wv.x+bv [B][C][N] bf16.
// attn: grid 1024 = (b, 32q-tile), 4 waves, wave = 32q x j-quarter, 32 steps
//   of 32 j, software-pipelined, wave-private stride-96 P (bank-uniform),
//   no barriers in main loop.

#define B_   8
#define C_   64
#define N_   4096
#define LOG2E 1.44269504088896340736f

typedef short bf16x8 __attribute__((ext_vector_type(8)));
typedef short bf16x4 __attribute__((ext_vector_type(4)));
typedef float f32x4  __attribute__((ext_vector_type(4)));
typedef unsigned int uint32;

#if __has_builtin(__builtin_amdgcn_exp2f)
#define EXP2(x) __builtin_amdgcn_exp2f(x)
#else
#define EXP2(x) __expf((x) * 0.69314718055994530942f)
#endif

__device__ __forceinline__ unsigned short f2bf_rn(float f) {
    union { __hip_bfloat16 h; unsigned short u; } cv;
    cv.h = __float2bfloat16(f);
    return cv.u;
}
__device__ __forceinline__ uint32 pk_rn(float lo, float hi) {
    return (uint32)f2bf_rn(lo) | ((uint32)f2bf_rn(hi) << 16);
}
// RTZ pack (1 v_perm): truncation bias cancels in softmax ratio (R2-R5 proven)
__device__ __forceinline__ uint32 pack_rtz(float lo, float hi) {
    return __builtin_amdgcn_perm(__float_as_uint(hi), __float_as_uint(lo), 0x07060302);
}

// ---------------------------------------------------------------------------
// prep (R5 verbatim, verified): all-MFMA QKV.
// ---------------------------------------------------------------------------
__global__ __launch_bounds__(256) void prep_kernel(
    const float* __restrict__ x,
    const float* __restrict__ wq, const float* __restrict__ bq,
    const float* __restrict__ wk, const float* __restrict__ bk,
    const float* __restrict__ wv, const float* __restrict__ bv,
    unsigned short* __restrict__ Qp, unsigned short* __restrict__ Kp,
    unsigned short* __restrict__ V)
{
    __shared__ __align__(16) unsigned short Wb[80 * 72];
    __shared__ __align__(16) unsigned short xT[64 * 72];

    const int t  = threadIdx.x;
    const int b  = blockIdx.x >> 6;
    const int p0 = (blockIdx.x & 63) << 6;

    for (int i = t; i < 5120; i += 256) {
        int o = i >> 6;
        float v = (o < 8) ? wq[i] * LOG2E : (o < 16) ? wk[i - 512] : wv[i - 1024];
        Wb[o * 72 + (i & 63)] = f2bf_rn(v);
    }
    for (int i = t; i < 2048; i += 256) {
        int c = i >> 5, p2 = (i & 31) << 1;
        float2 v = *(const float2*)(x + ((size_t)b * C_ + c) * N_ + p0 + p2);
        xT[p2 * 72 + c]       = f2bf_rn(v.x);
        xT[(p2 + 1) * 72 + c] = f2bf_rn(v.y);
    }
    __syncthreads();

    const int w = t >> 6, lane = t & 63, l16 = lane & 15, qd = lane >> 4;

    bf16x8 bfr[2];
    #pragma unroll
    for (int ks = 0; ks < 2; ++ks)
        bfr[ks] = *(const bf16x8*)(xT + (w * 16 + l16) * 72 + ks * 32 + qd * 8);
    const int px = p0 + w * 16 + l16;

    {   // Q/K rows 0..15
        f32x4 acc;
        #pragma unroll
        for (int r = 0; r < 4; ++r) {
            int o = qd * 4 + r;
            acc[r] = (o < 8) ? bq[o] * LOG2E : bk[o - 8];
        }
        bf16x8 af0 = *(const bf16x8*)(Wb + l16 * 72 + qd * 8);
        bf16x8 af1 = *(const bf16x8*)(Wb + l16 * 72 + 32 + qd * 8);
        acc = __builtin_amdgcn_mfma_f32_16x16x32_bf16(af0, bfr[0], acc, 0, 0, 0);
        acc = __builtin_amdgcn_mfma_f32_16x16x32_bf16(af1, bfr[1], acc, 0, 0, 0);
        uint2 u;
        u.x = pk_rn(acc[0], acc[1]);
        u.y = pk_rn(acc[2], acc[3]);
        unsigned short* base = (qd < 2) ? Qp : Kp;
        size_t row = ((size_t)b * N_ + px) * 16;
        *(uint2*)(base + row + (qd & 1) * 4) = u;
        uint2 z; z.x = 0; z.y = 0;
        *(uint2*)(base + row + 8 + (qd & 1) * 4) = z;   // zero ch 8-15
    }
    #pragma unroll
    for (int mt = 1; mt < 5; ++mt) {   // V rows
        const int ch = mt * 16 + qd * 4 - 16;
        f32x4 acc = {bv[ch], bv[ch + 1], bv[ch + 2], bv[ch + 3]};
        bf16x8 af0 = *(const bf16x8*)(Wb + (mt * 16 + l16) * 72 + qd * 8);
        bf16x8 af1 = *(const bf16x8*)(Wb + (mt * 16 + l16) * 72 + 32 + qd * 8);
        acc = __builtin_amdgcn_mfma_f32_16x16x32_bf16(af0, bfr[0], acc, 0, 0, 0);
        acc = __builtin_amdgcn_mfma_f32_16x16x32_bf16(af1, bfr[1], acc, 0, 0, 0);
        #pragma unroll
        for (int r = 0; r < 4; ++r)
            V[((size_t)b * C_ + ch + r) * N_ + px] = f2bf_rn(acc[r]);
    }
}

// ---------------------------------------------------------------------------
// attn. Grid 1024 = (b, 32q), 256 thr = 4 waves, wave = j-quarter.
// NOTE: plain __launch_bounds__(256) -- forcing min-waves=4 caused the R7
// scratch-spill regression (WRITE_SIZE 235 MB).
// ---------------------------------------------------------------------------
__global__ __launch_bounds__(256) void attn_mfma5_kernel(
    const unsigned short* __restrict__ Qp,
    const unsigned short* __restrict__ Kp,
    const unsigned short* __restrict__ Vb,
    float* __restrict__ out)
{
    // P: wave*6144 + buf*3072 + qt*1536 + l16*96 (+ jt*32 + qd*8 wr / qd*16 rd)
    // Dn at 24576 (4 waves x 32 q fp32); epilogue reduce reuses [0, 8192)
    __shared__ __align__(16) char smem[25088];

    const int t    = threadIdx.x;
    const int w    = t >> 6;
    const int lane = t & 63;
    const int l16  = lane & 15;
    const int qd   = lane >> 4;
    const int b    = blockIdx.x >> 7;          // 128 q-tiles per batch
    const int i0   = (blockIdx.x & 127) << 5;  // 32 queries

    const f32x4 zf = {};

    // Q frags (B-operand of K=16 MFMA), rows zero-padded ch 8-15
    bf16x4 qf[2];
    #pragma unroll
    for (int qt = 0; qt < 2; ++qt)
        qf[qt] = *(const bf16x4*)(Qp + ((size_t)b * N_ + i0 + qt * 16 + l16) * 16 + qd * 4);

    const unsigned short* Kq = Kp + ((size_t)b * N_ + w * 1024) * 16;
    const unsigned short* Vq = Vb + (size_t)b * C_ * N_ + w * 1024;

    char* PW = smem + w * 6144;
    const int wr = l16 * 96 + (qd << 3);   // + jt*32 bytes; b64 writes 4 dw/bank
    const int rd = l16 * 96 + (qd << 4);   // b128 reads 8 dw/bank

    f32x4 acc[2][4];   // [qt][ct]: O^T rows c=ct*16+qd*4+r, col q=qt*16+l16
    #pragma unroll
    for (int qt = 0; qt < 2; ++qt)
        #pragma unroll
        for (int ct = 0; ct < 4; ++ct) acc[qt][ct] = zf;
    float dsum[2] = {0.f, 0.f};

    bf16x4 kf[2][2];
    bf16x8 vf[2][4];

    // ---- prologue: step 0 P, prefetch step 1 ----
    #pragma unroll
    for (int jt = 0; jt < 2; ++jt)
        kf[0][jt] = *(const bf16x4*)(Kq + (size_t)(jt * 16 + l16) * 16 + qd * 4);
    #pragma unroll
    for (int ct = 0; ct < 4; ++ct)
        vf[0][ct] = *(const bf16x8*)(Vq + (size_t)(ct * 16 + l16) * N_ + qd * 8);

    #pragma unroll
    for (int jt = 0; jt < 2; ++jt) {
        f32x4 sf[2];
        #pragma unroll
        for (int qt = 0; qt < 2; ++qt)
            sf[qt] = __builtin_amdgcn_mfma_f32_16x16x16bf16_1k(kf[0][jt], qf[qt], zf, 0, 0, 0);
        #pragma unroll
        for (int qt = 0; qt < 2; ++qt) {
            float e0 = EXP2(sf[qt][0]), e1 = EXP2(sf[qt][1]);
            float e2 = EXP2(sf[qt][2]), e3 = EXP2(sf[qt][3]);
            dsum[qt] += (e0 + e1) + (e2 + e3);
            uint2 u; u.x = pack_rtz(e0, e1); u.y = pack_rtz(e2, e3);
            *(uint2*)(PW + qt * 1536 + wr + jt * 32) = u;
        }
    }
    #pragma unroll
    for (int jt = 0; jt < 2; ++jt)
        kf[1][jt] = *(const bf16x4*)(Kq + (size_t)(32 + jt * 16 + l16) * 16 + qd * 4);
    #pragma unroll
    for (int ct = 0; ct < 4; ++ct)
        vf[1][ct] = *(const bf16x8*)(Vq + (size_t)(ct * 16 + l16) * N_ + 32 + qd * 8);

    // ---- main pipelined loop ----
    #pragma unroll 2
    for (int s = 1; s < 32; ++s) {
        const int cur = s & 1, prv = cur ^ 1;
        const int jb = s * 32;

        // p2(s-1): read P(s-1), MFMA with V(s-1)
        bf16x8 pb[2];
        #pragma unroll
        for (int qt = 0; qt < 2; ++qt)
            pb[qt] = *(const bf16x8*)(PW + prv * 3072 + qt * 1536 + rd);
        #pragma unroll
        for (int qt = 0; qt < 2; ++qt)
            #pragma unroll
            for (int ct = 0; ct < 4; ++ct)
                acc[qt][ct] = __builtin_amdgcn_mfma_f32_16x16x32_bf16(vf[prv][ct], pb[qt], acc[qt][ct], 0, 0, 0);

        // prefetch step s+1 into freed slots
        if (s < 31) {
            #pragma unroll
            for (int jt = 0; jt < 2; ++jt)
                kf[prv][jt] = *(const bf16x4*)(Kq + (size_t)(jb + 32 + jt * 16 + l16) * 16 + qd * 4);
            #pragma unroll
            for (int ct = 0; ct < 4; ++ct)
                vf[prv][ct] = *(const bf16x8*)(Vq + (size_t)(ct * 16 + l16) * N_ + jb + 32 + qd * 8);
        }

        // p1(s) + exp + write P(s)
        #pragma unroll
        for (int jt = 0; jt < 2; ++jt) {
            f32x4 sf[2];
            #pragma unroll
            for (int qt = 0; qt < 2; ++qt)
                sf[qt] = __builtin_amdgcn_mfma_f32_16x16x16bf16_1k(kf[cur][jt], qf[qt], zf, 0, 0, 0);
            #pragma unroll
            for (int qt = 0; qt < 2; ++qt) {
                float e0 = EXP2(sf[qt][0]), e1 = EXP2(sf[qt][1]);
                float e2 = EXP2(sf[qt][2]), e3 = EXP2(sf[qt][3]);
                dsum[qt] += (e0 + e1) + (e2 + e3);
                uint2 u; u.x = pack_rtz(e0, e1); u.y = pack_rtz(e2, e3);
                *(uint2*)(PW + cur * 3072 + qt * 1536 + wr + jt * 32) = u;
            }
        }
    }

    // ---- pipeline epilogue: p2(31) ----
    {
        bf16x8 pb[2];
        #pragma unroll
        for (int qt = 0; qt < 2; ++qt)
            pb[qt] = *(const bf16x8*)(PW + 3072 + qt * 1536 + rd);
        #pragma unroll
        for (int qt = 0; qt < 2; ++qt)
            #pragma unroll
            for (int ct = 0; ct < 4; ++ct)
                acc[qt][ct] = __builtin_amdgcn_mfma_f32_16x16x32_bf16(vf[1][ct], pb[qt], acc[qt][ct], 0, 0, 0);
    }

    // ---- denominator partials -> Dn[w][q] ----
    float* Dn = (float*)(smem + 24576);
    #pragma unroll
    for (int qt = 0; qt < 2; ++qt) {
        float v = dsum[qt];
        v += __shfl_xor(v, 16, 64);
        v += __shfl_xor(v, 32, 64);
        if (qd == 0) Dn[w * 32 + qt * 16 + l16] = v;
    }
    __syncthreads();

    // ---- 3-round cross-wave acc reduction into wave 0 ----
    float* rb = (float*)smem;
    #pragma unroll
    for (int rnd = 1; rnd < 4; ++rnd) {
        if (w == rnd) {
            #pragma unroll
            for (int qt = 0; qt < 2; ++qt)
                #pragma unroll
                for (int ct = 0; ct < 4; ++ct)
                    *(f32x4*)(rb + ((qt * 4 + ct) * 64 + lane) * 4) = acc[qt][ct];
        }
        __syncthreads();
        if (w == 0) {
            #pragma unroll
            for (int qt = 0; qt < 2; ++qt)
                #pragma unroll
                for (int ct = 0; ct < 4; ++ct) {
                    f32x4 p = *(const f32x4*)(rb + ((qt * 4 + ct) * 64 + lane) * 4);
                    acc[qt][ct] += p;
                }
        }
        __syncthreads();
    }

    if (w == 0) {
        #pragma unroll
        for (int qt = 0; qt < 2; ++qt) {
            const int q = qt * 16 + l16;
            const float inv = 1.0f / (Dn[q] + Dn[32 + q] + Dn[64 + q] + Dn[96 + q]);
            #pragma unroll
            for (int ct = 0; ct < 4; ++ct)
                #pragma unroll
                for (int r = 0; r < 4; ++r)
                    out[((size_t)b * C_ + ct * 16 + qd * 4 + r) * N_ + i0 + q] = acc[qt][ct][r] * inv;
        }
    }
}

// ---------------------------------------------------------------------------
// Fallback (workspace too small): round-1 fused fp32 flash kernel (verified).
// ---------------------------------------------------------------------------
__global__ __launch_bounds__(256) void attn_fused_fallback(
    const float* __restrict__ x,
    const float* __restrict__ wq, const float* __restrict__ bq,
    const float* __restrict__ wk, const float* __restrict__ bk,
    const float* __restrict__ wv, const float* __restrict__ bv,
    float* __restrict__ out)
{
    __shared__ float Qs[64][8];
    __shared__ float Ks[8][64];
    __shared__ float Vs[64][C_];
    __shared__ float Ws[64][64 + 1];
    __shared__ float Xs[C_ * 64];
    __shared__ float Wks[8][C_];
    __shared__ float Wvs[C_][C_ + 1];

    const int t     = threadIdx.x;
    const int b     = blockIdx.x / (N_ / 64);
    const int i0    = (blockIdx.x % (N_ / 64)) * 64;
    const int jlane = t & 63;
    const int wgrp  = t >> 6;

    for (int l = t; l < 8 * C_;  l += 256) Wks[l >> 6][l & 63] = wk[l];
    for (int l = t; l < C_ * C_; l += 256) Wvs[l >> 6][l & 63] = wv[l];
    for (int l = t; l < C_ * 64; l += 256)
        Xs[(l >> 6) * 64 + (l & 63)] = x[((size_t)b * C_ + (l >> 6)) * N_ + i0 + (l & 63)];
    __syncthreads();
    {
        int qi = jlane;
        #pragma unroll
        for (int r = 0; r < 2; ++r) {
            int cc = wgrp * 2 + r;
            float a = bq[cc];
            for (int c = 0; c < C_; ++c) a += wq[cc * C_ + c] * Xs[c * 64 + qi];
            Qs[qi][cc] = a;
        }
    }
    __syncthreads();

    const int qi2 = t >> 2;
    const int cb  = (t & 3) << 4;
    float accv[16];
    #pragma unroll
    for (int r = 0; r < 16; ++r) accv[r] = 0.f;
    float denom = 0.f;

    for (int j0 = 0; j0 < N_; j0 += 64) {
        for (int l = t; l < C_ * 64; l += 256)
            Xs[(l >> 6) * 64 + (l & 63)] = x[((size_t)b * C_ + (l >> 6)) * N_ + j0 + (l & 63)];
        __syncthreads();
        {
            int j = jlane;
            #pragma unroll
            for (int r = 0; r < 2; ++r) {
                int cc = wgrp * 2 + r;
                float a = bk[cc];
                for (int c = 0; c < C_; ++c) a += Wks[cc][c] * Xs[c * 64 + j];
                Ks[cc][j] = a;
            }
        }
        {
            int vc = jlane;
            #pragma unroll 2
            for (int r = 0; r < 16; ++r) {
                int j = wgrp * 16 + r;
                float a = bv[vc];
                for (int c = 0; c < C_; ++c) a += Wvs[vc][c] * Xs[c * 64 + j];
                Vs[j][vc] = a;
            }
        }
        __syncthreads();
        {
            float kreg[8];
            #pragma unroll
            for (int cc = 0; cc < 8; ++cc) kreg[cc] = Ks[cc][jlane];
            #pragma unroll 4
            for (int r = 0; r < 16; ++r) {
                int qi = wgrp * 16 + r;
                float e = 0.f;
                #pragma unroll
                for (int cc = 0; cc < 8; ++cc) e += Qs[qi][cc] * kreg[cc];
                Ws[qi][jlane] = __expf(e);
            }
        }
        __syncthreads();
        #pragma unroll 4
        for (int j = 0; j < 64; ++j) {
            float wv2 = Ws[qi2][j];
            denom += wv2;
            const float4* vrow = (const float4*)(&Vs[j][cb]);
            float4 v0 = vrow[0], v1 = vrow[1], v2 = vrow[2], v3 = vrow[3];
            accv[0]  += wv2 * v0.x; accv[1]  += wv2 * v0.y; accv[2]  += wv2 * v0.z; accv[3]  += wv2 * v0.w;
            accv[4]  += wv2 * v1.x; accv[5]  += wv2 * v1.y; accv[6]  += wv2 * v1.z; accv[7]  += wv2 * v1.w;
            accv[8]  += wv2 * v2.x; accv[9]  += wv2 * v2.y; accv[10] += wv2 * v2.z; accv[11] += wv2 * v2.w;
            accv[12] += wv2 * v3.x; accv[13] += wv2 * v3.y; accv[14] += wv2 * v3.z; accv[15] += wv2 * v3.w;
        }
        __syncthreads();
    }

    const float inv = 1.0f / denom;
    #pragma unroll
    for (int r = 0; r < 16; ++r)
        out[((size_t)b * C_ + cb + r) * N_ + i0 + qi2] = accv[r] * inv;
}

// ---------------------------------------------------------------------------
extern "C" void kernel_launch(void* const* d_in, const int* in_sizes, int n_in,
                              void* d_out, int out_size, void* d_ws, size_t ws_size,
                              hipStream_t stream)
{
    const float* x  = (const float*)d_in[0];
    const float* wq = (const float*)d_in[1];
    const float* bq = (const float*)d_in[2];
    const float* wk = (const float*)d_in[3];
    const float* bk = (const float*)d_in[4];
    const float* wv = (const float*)d_in[5];
    const float* bv = (const float*)d_in[6];
    float* out = (float*)d_out;

    const size_t nQ = (size_t)B_ * N_ * 16;       // 512K elems (1 MB)
    const size_t nV = (size_t)B_ * C_ * N_;       // 2M elems (4 MB)
    const size_t needed = (2 * nQ + nV) * sizeof(unsigned short);   // 6 MB

    if (ws_size >= needed) {
        unsigned short* Qp = (unsigned short*)d_ws;
        unsigned short* Kp = Qp + nQ;
        unsigned short* Vb = Kp + nQ;
        prep_kernel<<<B_ * (N_ / 64), 256, 0, stream>>>(x, wq, bq, wk, bk, wv, bv,
                                                        Qp, Kp, Vb);
        attn_mfma5_kernel<<<B_ * (N_ / 32), 256, 0, stream>>>(Qp, Kp, Vb, out);
    } else {
        attn_fused_fallback<<<B_ * (N_ / 64), 256, 0, stream>>>(x, wq, bq, wk, bk, wv, bv, out);
    }
}